// Round 1
// baseline (241.944 us; speedup 1.0000x reference)
//
#include <hip/hip_runtime.h>

// ZeroPad2d: in [32,2048,2048] f32 -> out [32,2050,2050] f32, pad=1 all around.
// Memory-bound copy. Output written in aligned float4 chunks; interior chunks
// take a single 16B (4B-aligned) input load; borders/zero rows handled on a
// rare slow path. Every output element is written every call (harness does not
// re-zero d_out between timed replays).

#define CC 32
#define HH 2048
#define WW 2048
#define HP 2050
#define WP 2050

typedef float f32x4 __attribute__((ext_vector_type(4)));

__global__ __launch_bounds__(256) void zeropad_kernel(const float* __restrict__ in,
                                                      float* __restrict__ out,
                                                      unsigned nchunks) {
    const unsigned stride = gridDim.x * blockDim.x;
    for (unsigned chunk = blockIdx.x * blockDim.x + threadIdx.x; chunk < nchunks;
         chunk += stride) {
        const unsigned o  = chunk * 4u;        // flat output index of chunk start
        const unsigned r  = o / WP;            // global row id in [0, CC*HP)
        const unsigned x0 = o - r * WP;        // column of first element
        const unsigned c  = r / HP;            // channel
        const unsigned y  = r - c * HP;        // padded-row within channel

        f32x4 v;
        if (x0 + 3u < WP) {
            // chunk entirely within one output row
            if (y >= 1u && y <= (unsigned)HH && x0 >= 1u && x0 + 3u <= (unsigned)WW) {
                // fully interior: 4 consecutive input floats, 4B-aligned 16B load
                const float* src = in + ((c * HH + (y - 1u)) * WW + (x0 - 1u));
                __builtin_memcpy(&v, src, 16);
            } else if (y == 0u || y == (unsigned)(HP - 1)) {
                v = (f32x4)0.f;                // top/bottom zero rows
            } else {
                // interior row but touches left/right border column
                #pragma unroll
                for (int j = 0; j < 4; ++j) {
                    unsigned x = x0 + (unsigned)j;
                    v[j] = (x >= 1u && x <= (unsigned)WW)
                               ? in[(c * HH + (y - 1u)) * WW + (x - 1u)]
                               : 0.f;
                }
            }
        } else {
            // chunk crosses a row (possibly channel) boundary — fully general
            #pragma unroll
            for (int j = 0; j < 4; ++j) {
                unsigned x = x0 + (unsigned)j, yy = y, cc = c;
                if (x >= (unsigned)WP) {
                    x -= (unsigned)WP;
                    yy += 1u;
                    if (yy >= (unsigned)HP) { yy = 0u; cc += 1u; }
                }
                bool interior = (yy >= 1u && yy <= (unsigned)HH &&
                                 x >= 1u && x <= (unsigned)WW);
                v[j] = interior ? in[(cc * HH + (yy - 1u)) * WW + (x - 1u)] : 0.f;
            }
        }
        *(f32x4*)(out + o) = v;                // o % 4 == 0 -> aligned dwordx4
    }
}

extern "C" void kernel_launch(void* const* d_in, const int* in_sizes, int n_in,
                              void* d_out, int out_size, void* d_ws, size_t ws_size,
                              hipStream_t stream) {
    const float* in = (const float*)d_in[0];
    float* out = (float*)d_out;
    const unsigned nchunks = (unsigned)(out_size / 4);   // 33,620,000
    const int threads = 256;
    const int blocks = 2048;                              // 8 blocks/CU, grid-stride
    zeropad_kernel<<<blocks, threads, 0, stream>>>(in, out, nchunks);
}

// Round 2
// 200.059 us; speedup vs baseline: 1.2094x; 1.2094x over previous
//
#include <hip/hip_runtime.h>

// ZeroPad2d: in [32,2048,2048] f32 -> out [32,2050,2050] f32, pad=1.
// Row-mapped memory-bound copy:
//   - one 256-thread block per input row (32*2048 = 65536 rows)
//   - c = bid>>11, h = bid&2047 (H, W are pow2 -> no divides, uniform SALU)
//   - each thread: 2 independent 16B-aligned loads, then 2 stores (4B-aligned,
//     legal for global_store_dwordx4; L2 merges the split cachelines)
//   - lane 0 writes the left/right zero border of its row
//   - 64 trailing blocks zero the top/bottom pad rows
// Every output element is written on every call (harness does not re-poison).

#define CH 32
#define H  2048
#define W  2048
#define HPAD 2050
#define WPAD 2050

typedef float f32x4 __attribute__((ext_vector_type(4)));

__global__ __launch_bounds__(256) void zeropad_rows(const float* __restrict__ in,
                                                    float* __restrict__ out) {
    const unsigned bid = blockIdx.x;
    const unsigned t   = threadIdx.x;

    if (bid < CH * H) {
        // ---- interior row copy ----
        const unsigned c = bid >> 11;          // row / 2048
        const unsigned h = bid & 2047u;        // row % 2048
        const float* src = in + ((size_t)bid << 11);                    // bid * 2048
        float*       dst = out + (size_t)(c * HPAD + h + 1u) * WPAD + 1u;

        // 2048 floats per row = 512 float4 chunks; thread t takes chunks t, t+256
        f32x4 a = *(const f32x4*)(src + 4u * t);            // 16B-aligned load
        f32x4 b = *(const f32x4*)(src + 4u * t + 1024u);    // 16B-aligned load
        __builtin_memcpy(dst + 4u * t,          &a, 16);    // 4B-aligned store
        __builtin_memcpy(dst + 4u * t + 1024u,  &b, 16);

        if (t == 0) {
            dst[-1]   = 0.f;    // x = 0 (left pad)
            dst[2048] = 0.f;    // x = 2049 (right pad)
        }
    } else {
        // ---- top/bottom zero pad rows: 32 channels x 2 rows ----
        const unsigned idx = bid - CH * H;     // 0..63
        const unsigned c   = idx >> 1;
        const unsigned y   = (idx & 1u) ? (HPAD - 1u) : 0u;
        float* dst = out + (size_t)(c * HPAD + y) * WPAD;

        f32x4 z = (f32x4)0.f;
        __builtin_memcpy(dst + 8u * t,      &z, 16);        // floats [8t, 8t+4)
        __builtin_memcpy(dst + 8u * t + 4u, &z, 16);        // floats [8t+4, 8t+8)
        if (t == 0) {
            dst[2048] = 0.f;
            dst[2049] = 0.f;
        }
    }
}

extern "C" void kernel_launch(void* const* d_in, const int* in_sizes, int n_in,
                              void* d_out, int out_size, void* d_ws, size_t ws_size,
                              hipStream_t stream) {
    const float* in = (const float*)d_in[0];
    float* out = (float*)d_out;
    const int blocks = CH * H + CH * 2;        // 65536 copy rows + 64 zero rows
    zeropad_rows<<<blocks, 256, 0, stream>>>(in, out);
}